// Round 2
// baseline (223.652 us; speedup 1.0000x reference)
//
#include <hip/hip_runtime.h>

// Integrate-and-fire SNN forward (IF_88957362634870).
// x: 8 frames of N = 4,194,304 fp32 (16 MiB each); out: 8 frames.
//
// Session evidence: write path does 6.6 TB/s (fill, phase-3 kernel), but
// every structure reading x from HBM/IF$ caps at 2.1-2.5 TB/s -- including
// the HIP runtime's own d_in restore copy (~2.8 TB/s combined). MLP, stream
// count, NT stores, and device-wide lockstep are all ruled out. Untested
// read-side variable: ~50% of reads hit IF$ (FETCH 65.5 of 134 MB). R10
// isolates it: nontemporal LOADS stream around L2/IF$ (FETCH should jump to
// ~134 MB). Also fold everything back into ONE kernel: elementwise op never
// needed the split; closed-form phase 3 (out[t][i] = thre*[sc[i] >=
// (t+1)*thre - eps], exact at thre=2^-3, verified R7/R8) + NT stores.

#define T1 8
#define T2 8
#define L_DIV 8.0f
#define EPS_C (-8e-05f)
#define G 2            // float4-groups per thread

typedef float fvec4 __attribute__((ext_vector_type(4)));

__global__ __launch_bounds__(256) void if_fwd_fused(
    const fvec4* __restrict__ x,
    const float* __restrict__ thresh,
    fvec4* __restrict__ out,
    int n4)
{
    const int base = blockIdx.x * (256 * G) + threadIdx.x;
    const float thre = thresh[0] / L_DIV;

    // All 16 loads nontemporal: stream around L2/IF$, straight from HBM.
    fvec4 xv[G][T1];
    #pragma unroll
    for (int t = 0; t < T1; ++t)
        #pragma unroll
        for (int g = 0; g < G; ++g)
            xv[g][t] = __builtin_nontemporal_load(&x[(size_t)t * n4 + base + g * 256]);

    float m[G][4], sc[G][4];
    #pragma unroll
    for (int g = 0; g < G; ++g)
        #pragma unroll
        for (int k = 0; k < 4; ++k) { m[g][k] = 0.5f * thre; sc[g][k] = 0.0f; }

    // Phase 1: integrate T1 frames, fire-and-subtract.
    #pragma unroll
    for (int t = 0; t < T1; ++t)
        #pragma unroll
        for (int g = 0; g < G; ++g)
            #pragma unroll
            for (int k = 0; k < 4; ++k) {
                m[g][k] += xv[g][t][k];
                const float spike = (m[g][k] - thre >= EPS_C) ? thre : 0.0f;
                m[g][k] -= spike;
                sc[g][k] += spike;
            }

    // Phase 2: 7 relaxation steps with reverse spikes (register-only).
    #pragma unroll
    for (int t = 0; t < T1 - 1; ++t)
        #pragma unroll
        for (int g = 0; g < G; ++g)
            #pragma unroll
            for (int k = 0; k < 4; ++k) {
                const float spike = (m[g][k] - thre >= EPS_C) ? thre : 0.0f;
                const float rev   = (-m[g][k] > 0.0f) ? thre : 0.0f;
                m[g][k] = m[g][k] - spike + rev;
                sc[g][k] += spike - rev;
            }

    // Phase 3 (closed form, verified R7/R8): fires are a prefix in t.
    // out[t][i] = thre * [ sc[i] - (t+1)*thre >= EPS ]; exact at thre=2^-3.
    #pragma unroll
    for (int t = 0; t < T2; ++t) {
        const float cut = (float)(t + 1) * thre;
        #pragma unroll
        for (int g = 0; g < G; ++g) {
            fvec4 o;
            #pragma unroll
            for (int k = 0; k < 4; ++k)
                o[k] = (sc[g][k] - cut >= EPS_C) ? thre : 0.0f;
            __builtin_nontemporal_store(o, &out[(size_t)t * n4 + base + g * 256]);
        }
    }
}

extern "C" void kernel_launch(void* const* d_in, const int* in_sizes, int n_in,
                              void* d_out, int out_size, void* d_ws, size_t ws_size,
                              hipStream_t stream) {
    const fvec4* x      = (const fvec4*)d_in[0];
    const float* thresh = (const float*)d_in[1];
    fvec4*       out    = (fvec4*)d_out;

    const int N  = in_sizes[0] / T1;  // 4,194,304
    const int n4 = N / 4;             // 1,048,576

    const int block = 256;
    const int grid  = n4 / (block * G);  // 2048
    if_fwd_fused<<<grid, block, 0, stream>>>(x, thresh, out, n4);
}